// Round 8
// baseline (144.840 us; speedup 1.0000x reference)
//
#include <hip/hip_runtime.h>
#include <hip/hip_bf16.h>

#define NB 128
#define LL 512
#define DD 512

typedef __attribute__((ext_vector_type(4))) float  f32x4;
typedef __attribute__((ext_vector_type(8))) short  s16x8;

__device__ __forceinline__ short f2bf(float f) {
    __hip_bfloat16 h = __float2bfloat16(f);
    return *reinterpret_cast<short*>(&h);
}

// monotone float<->uint mapping so atomicMax(uint) == float max
__device__ __forceinline__ unsigned fmap(float f) {
    unsigned u = __float_as_uint(f);
    return (u & 0x80000000u) ? ~u : (u | 0x80000000u);
}
__device__ __forceinline__ float funmap(unsigned u) {
    unsigned b = (u & 0x80000000u) ? (u ^ 0x80000000u) : ~u;
    return __uint_as_float(b);
}

__global__ __launch_bounds__(256) void init_kernel(unsigned* __restrict__ p, int n) {
    int i = blockIdx.x * 256 + threadIdx.x;
    if (i < n) p[i] = 0u;  // 0 < fmap of any real value
}

// Fused: 128x128x512 GEMM + on-the-fly sum-of-squares + inv-norm scaling +
// masked row/col max.
// Staging converts fp32 -> bf16 ONCE (reg path: load -> SS-accum -> cvt ->
// swizzled ds_write_b128). LDS holds bf16: 128 rows x 64 k x 2 B = 16 KB per
// matrix -> 32 KB single buffer, split barrier, 4 blocks/CU.
__global__ __launch_bounds__(256, 4) void simgemm_fused(
        const float* __restrict__ x1, const float* __restrict__ x2,
        const int* __restrict__ mask1, const int* __restrict__ mask2,
        unsigned* __restrict__ rowmax_u, unsigned* __restrict__ colmax_u) {
    __shared__ __align__(16) char lds[33792];
    // A @0 (16KB bf16), B @16384 (16KB bf16), invA @32768, invB @33280
    char* As0 = lds;
    char* Bs0 = lds + 16384;
    float* invA_lds = reinterpret_cast<float*>(lds + 32768);
    float* invB_lds = reinterpret_cast<float*>(lds + 33280);

    int bid = blockIdx.x;
    int lid = (bid & 7) * 256 + (bid >> 3);   // XCD-chunked bijective swizzle (nwg=2048)
    int b   = lid >> 4;
    int tr  = (lid >> 2) & 3;
    int tc  = lid & 3;

    int tid  = threadIdx.x;
    int lane = tid & 63;
    int w    = tid >> 6;
    int wr = w >> 1, wc = w & 1;
    int l15 = lane & 15, lhi = lane >> 4;
    int rg3 = lane >> 3, sl = lane & 7;       // staging: 8 slot-lanes x 8 rows

    const float* Ab = x1 + ((size_t)b * LL + tr * 128) * DD;
    const float* Bb = x2 + ((size_t)b * LL + tc * 128) * DD;

    float ssa[4] = {0.f, 0.f, 0.f, 0.f};
    float ssb[4] = {0.f, 0.f, 0.f, 0.f};

    f32x4 acc[4][4];
    #pragma unroll
    for (int fr = 0; fr < 4; ++fr)
        #pragma unroll
        for (int fc = 0; fc < 4; ++fc) {
            acc[fr][fc].x = 0.f; acc[fr][fc].y = 0.f;
            acc[fr][fc].z = 0.f; acc[fr][fc].w = 0.f;
        }

    // Stage one 128x64 K-tile of one matrix: thread (w, rg3, sl) handles
    // rows w*32 + i*8 + rg3 (i=0..3), bf16 cols sl*8..sl*8+7.
    // Load phase first (8 independent dwordx4 in flight), then cvt+SS+write.
    #define STAGE(src, dst, ss, t)                                                \
        {                                                                         \
            f32x4 v[4][2];                                                        \
            _Pragma("unroll")                                                     \
            for (int i = 0; i < 4; ++i) {                                         \
                int row = w * 32 + i * 8 + rg3;                                   \
                const float* g = (src) + (size_t)row * DD + (t) * 64 + sl * 8;    \
                v[i][0] = *reinterpret_cast<const f32x4*>(g);                     \
                v[i][1] = *reinterpret_cast<const f32x4*>(g + 4);                 \
            }                                                                     \
            _Pragma("unroll")                                                     \
            for (int i = 0; i < 4; ++i) {                                         \
                int row = w * 32 + i * 8 + rg3;                                   \
                f32x4 v0 = v[i][0], v1 = v[i][1];                                 \
                ss[i] += v0.x*v0.x + v0.y*v0.y + v0.z*v0.z + v0.w*v0.w            \
                       + v1.x*v1.x + v1.y*v1.y + v1.z*v1.z + v1.w*v1.w;           \
                s16x8 o;                                                          \
                o[0] = f2bf(v0.x); o[1] = f2bf(v0.y);                             \
                o[2] = f2bf(v0.z); o[3] = f2bf(v0.w);                             \
                o[4] = f2bf(v1.x); o[5] = f2bf(v1.y);                             \
                o[6] = f2bf(v1.z); o[7] = f2bf(v1.w);                             \
                unsigned byte = (unsigned)(row * 128 + sl * 16)                   \
                              ^ ((unsigned)(row & 7) << 4);                       \
                *reinterpret_cast<s16x8*>((dst) + byte) = o;                      \
            }                                                                     \
        }

    STAGE(Ab, As0, ssa, 0);
    STAGE(Bb, Bs0, ssb, 0);
    __syncthreads();

    for (int t = 0; t < 8; ++t) {
        // compute on the staged tile: 16 ds_read_b128 + 32 MFMA per wave
        #pragma unroll
        for (int ks = 0; ks < 2; ++ks) {
            s16x8 af[4], bf[4];
            #pragma unroll
            for (int fr = 0; fr < 4; ++fr) {
                int row = wr * 64 + fr * 16 + l15;
                unsigned byte = (unsigned)(row * 128 + ks * 64 + lhi * 16)
                              ^ ((unsigned)(row & 7) << 4);
                af[fr] = *reinterpret_cast<const s16x8*>(As0 + byte);
            }
            #pragma unroll
            for (int fc = 0; fc < 4; ++fc) {
                int crow = wc * 64 + fc * 16 + l15;
                unsigned byte = (unsigned)(crow * 128 + ks * 64 + lhi * 16)
                              ^ ((unsigned)(crow & 7) << 4);
                bf[fc] = *reinterpret_cast<const s16x8*>(Bs0 + byte);
            }
            __builtin_amdgcn_s_setprio(1);
            #pragma unroll
            for (int fr = 0; fr < 4; ++fr)
                #pragma unroll
                for (int fc = 0; fc < 4; ++fc)
                    acc[fr][fc] = __builtin_amdgcn_mfma_f32_16x16x32_bf16(
                        af[fr], bf[fc], acc[fr][fc], 0, 0, 0);
            __builtin_amdgcn_s_setprio(0);
        }
        __syncthreads();                   // all reads of tile t done
        if (t < 7) {
            STAGE(Ab, As0, ssa, t + 1);    // overwrite with tile t+1
            STAGE(Bb, Bs0, ssb, t + 1);
            __syncthreads();               // writes visible block-wide
        }
    }

    // ---- inv norms: each row's SS is spread across its 8 slot-lanes ----
    #pragma unroll
    for (int i = 0; i < 4; ++i) {
        ssa[i] += __shfl_xor(ssa[i], 1, 64);
        ssa[i] += __shfl_xor(ssa[i], 2, 64);
        ssa[i] += __shfl_xor(ssa[i], 4, 64);
        ssb[i] += __shfl_xor(ssb[i], 1, 64);
        ssb[i] += __shfl_xor(ssb[i], 2, 64);
        ssb[i] += __shfl_xor(ssb[i], 4, 64);
    }
    if (sl == 0) {
        #pragma unroll
        for (int i = 0; i < 4; ++i) {
            int row = w * 32 + i * 8 + rg3;
            invA_lds[row] = 1.0f / fmaxf(sqrtf(ssa[i]), 1e-8f);
            invB_lds[row] = 1.0f / fmaxf(sqrtf(ssb[i]), 1e-8f);
        }
    }
    __syncthreads();

    // ---- scale by inv norms ----
    float ia[4][4], ib4[4];
    #pragma unroll
    for (int fr = 0; fr < 4; ++fr)
        #pragma unroll
        for (int r = 0; r < 4; ++r)
            ia[fr][r] = invA_lds[wr * 64 + fr * 16 + lhi * 4 + r];
    #pragma unroll
    for (int fc = 0; fc < 4; ++fc)
        ib4[fc] = invB_lds[wc * 64 + fc * 16 + l15];
    #pragma unroll
    for (int fr = 0; fr < 4; ++fr)
        #pragma unroll
        for (int fc = 0; fc < 4; ++fc)
            #pragma unroll
            for (int r = 0; r < 4; ++r)
                acc[fr][fc][r] *= ia[fr][r] * ib4[fc];

    // ---- epilogue: masked row/col maxes ----
    int m2[4];
    #pragma unroll
    for (int fc = 0; fc < 4; ++fc)
        m2[fc] = mask2[b * LL + tc * 128 + wc * 64 + fc * 16 + l15];
    int m1[4][4];
    #pragma unroll
    for (int fr = 0; fr < 4; ++fr)
        #pragma unroll
        for (int r = 0; r < 4; ++r)
            m1[fr][r] = mask1[b * LL + tr * 128 + wr * 64 + fr * 16 + lhi * 4 + r];

    // row max: per (fr,r) max over this wave's 64 cols (mask2-gated)
    #pragma unroll
    for (int fr = 0; fr < 4; ++fr) {
        #pragma unroll
        for (int r = 0; r < 4; ++r) {
            float v = -INFINITY;
            #pragma unroll
            for (int fc = 0; fc < 4; ++fc)
                if (m2[fc]) v = fmaxf(v, acc[fr][fc][r]);
            v = fmaxf(v, __shfl_xor(v, 1, 64));
            v = fmaxf(v, __shfl_xor(v, 2, 64));
            v = fmaxf(v, __shfl_xor(v, 4, 64));
            v = fmaxf(v, __shfl_xor(v, 8, 64));
            if (l15 == 0)
                atomicMax(&rowmax_u[b * LL + tr * 128 + wr * 64 + fr * 16 + lhi * 4 + r],
                          fmap(v));
        }
    }
    // col max: per fc col, max over this wave's 64 rows (mask1-gated)
    #pragma unroll
    for (int fc = 0; fc < 4; ++fc) {
        float v = -INFINITY;
        #pragma unroll
        for (int fr = 0; fr < 4; ++fr)
            #pragma unroll
            for (int r = 0; r < 4; ++r)
                if (m1[fr][r]) v = fmaxf(v, acc[fr][fc][r]);
        v = fmaxf(v, __shfl_xor(v, 16, 64));
        v = fmaxf(v, __shfl_xor(v, 32, 64));
        if (lhi == 0)
            atomicMax(&colmax_u[b * LL + tc * 128 + wc * 64 + fc * 16 + l15], fmap(v));
    }
    #undef STAGE
}

__global__ __launch_bounds__(64) void finalize_kernel(
        const unsigned* __restrict__ rowmax_u, const unsigned* __restrict__ colmax_u,
        const int* __restrict__ mask1, const int* __restrict__ mask2,
        float* __restrict__ out) {
    int b = blockIdx.x;
    int lane = threadIdx.x;
    float s1 = 0.f, c1 = 0.f, s2 = 0.f, c2 = 0.f;
    for (int i = lane; i < LL; i += 64) {
        if (mask1[b * LL + i]) { s1 += funmap(rowmax_u[b * LL + i]); c1 += 1.f; }
        if (mask2[b * LL + i]) { s2 += funmap(colmax_u[b * LL + i]); c2 += 1.f; }
    }
    #pragma unroll
    for (int off = 32; off >= 1; off >>= 1) {
        s1 += __shfl_xor(s1, off, 64);
        c1 += __shfl_xor(c1, off, 64);
        s2 += __shfl_xor(s2, off, 64);
        c2 += __shfl_xor(c2, off, 64);
    }
    if (lane == 0) out[b] = 0.5f * (s1 / c1 + s2 / c2);
}

extern "C" void kernel_launch(void* const* d_in, const int* in_sizes, int n_in,
                              void* d_out, int out_size, void* d_ws, size_t ws_size,
                              hipStream_t stream) {
    const float* x1    = (const float*)d_in[0];
    const int*   mask1 = (const int*)d_in[1];
    const float* x2    = (const float*)d_in[2];
    const int*   mask2 = (const int*)d_in[3];
    float* out = (float*)d_out;

    unsigned* rowmax_u = (unsigned*)d_ws;
    unsigned* colmax_u = rowmax_u + NB * LL;

    init_kernel<<<(2 * NB * LL + 255) / 256, 256, 0, stream>>>(rowmax_u, 2 * NB * LL);
    simgemm_fused<<<NB * 16, 256, 0, stream>>>(x1, x2, mask1, mask2,
                                               rowmax_u, colmax_u);
    finalize_kernel<<<NB, 64, 0, stream>>>(rowmax_u, colmax_u, mask1, mask2, out);
}